// Round 1
// baseline (278.843 us; speedup 1.0000x reference)
//
#include <hip/hip_runtime.h>
#include <stdint.h>

typedef __bf16 bf16;
typedef bf16 bf16x8 __attribute__((ext_vector_type(8)));
typedef float f32x4 __attribute__((ext_vector_type(4)));

#define MFMA(a, b, c) __builtin_amdgcn_mfma_f32_16x16x32_bf16(a, b, c, 0, 0, 0)

// exp(0.25*s) = exp2(s * 0.25*log2(e)); scale folded into Qp at projection.
#define SCALE_L2E 0.3606737602222409f
#define M0 16.0f

__device__ __forceinline__ void gload_lds16(const void* g, void* l) {
  __builtin_amdgcn_global_load_lds(
      (const __attribute__((address_space(1))) uint32_t*)g,
      (__attribute__((address_space(3))) uint32_t*)l, 16, 0, 0);
}

// ---------------------------------------------------------------------------
// Kernel 1: Wt[z][n][k] = (bf16) W_z[k][n] — LDS-tiled transpose, coalesced
// both sides. grid (16,16,3), block (32,8).
// ---------------------------------------------------------------------------
__global__ void k_wtrans(const float* __restrict__ Wq, const float* __restrict__ Wk,
                         const float* __restrict__ Wv, bf16* __restrict__ Wt) {
  __shared__ float tile[32][33];
  int x = threadIdx.x, y = threadIdx.y;
  int k0 = blockIdx.x * 32, n0 = blockIdx.y * 32, z = blockIdx.z;
  const float* W = (z == 0) ? Wq : (z == 1) ? Wk : Wv;
  for (int j = 0; j < 4; j++)
    tile[y + 8 * j][x] = W[(size_t)(k0 + y + 8 * j) * 512 + n0 + x];
  __syncthreads();
  bf16* o = Wt + (size_t)z * 262144;
  for (int j = 0; j < 4; j++)
    o[(size_t)(n0 + y + 8 * j) * 512 + k0 + x] = (bf16)tile[x][y + 8 * j];
}

// ---------------------------------------------------------------------------
// Kernel 2: projection GEMM, BK=64, DOUBLE-BUFFERED prefetch pipeline.
// Per step t: issue tile t+1 loads (A f32->regs, B gload_lds), compute tile t,
// then cvt+ds_write A(t+1) (T14 split), single __syncthreads drains loads that
// were issued ~one compute-phase earlier (latency hidden under MFMA).
// As now uses the same XOR chunk swizzle as Bs (slot s holds chunk s^(row&7)).
// ---------------------------------------------------------------------------
__global__ __launch_bounds__(256, 2) void k_proj(
    const float* __restrict__ q, const float* __restrict__ k, const float* __restrict__ v,
    const bf16* __restrict__ Wt, const float* __restrict__ bq, const float* __restrict__ bk,
    const float* __restrict__ bv, bf16* __restrict__ Qp, bf16* __restrict__ Kp,
    bf16* __restrict__ Vtp) {
  int z = blockIdx.z;
  const float* A = (z == 0) ? q : (z == 1) ? k : v;
  const float* bias = (z == 0) ? bq : (z == 1) ? bk : bv;
  const bf16* Bw = Wt + (size_t)z * 262144;

  int m0 = blockIdx.x * 128, n0 = blockIdx.y * 128;
  __shared__ __align__(16) char smem[65536];
  bf16* As = (bf16*)smem;            // 2 x (128 x 64), swizzled
  bf16* Bs = (bf16*)(smem + 32768);  // 2 x (128 x 64), swizzled
  bf16* Ts = (bf16*)smem;            // epilogue reuse: 128 x 136

  int tid = threadIdx.x;
  int wave = tid >> 6, lane = tid & 63, qr = lane & 15, quad = lane >> 4;
  int wm = (wave >> 1) * 64, wn = (wave & 1) * 64;

  f32x4 acc[4][4];
  for (int mi = 0; mi < 4; mi++)
    for (int ni = 0; ni < 4; ni++) acc[mi][ni] = (f32x4){0.f, 0.f, 0.f, 0.f};

  float4 rx[4], ry[4];  // staged A f32 (in-flight across the compute phase)

  auto issue = [&](int kk, int buf) {
    // A f32 loads first (so writeA's auto vmcnt wait leaves B gloads in flight)
#pragma unroll
    for (int i = 0; i < 4; i++) {
      int ch = i * 256 + tid, row = ch >> 3, c = ch & 7;
      const float4* src = (const float4*)(A + (size_t)(m0 + row) * 512 + kk + c * 8);
      rx[i] = src[0];
      ry[i] = src[1];
    }
#pragma unroll
    for (int i = 0; i < 4; i++) {
      int ch = i * 256 + tid, row = ch >> 3, c = ch & 7, cs = c ^ (row & 7);
      gload_lds16(Bw + (size_t)(n0 + row) * 512 + kk + cs * 8, &Bs[buf * 8192 + ch * 8]);
    }
  };

  auto writeA = [&](int buf) {
#pragma unroll
    for (int i = 0; i < 4; i++) {
      int ch = i * 256 + tid, row = ch >> 3, c = ch & 7, cs = c ^ (row & 7);
      bf16x8 t;
      t[0] = (bf16)rx[i].x; t[1] = (bf16)rx[i].y; t[2] = (bf16)rx[i].z; t[3] = (bf16)rx[i].w;
      t[4] = (bf16)ry[i].x; t[5] = (bf16)ry[i].y; t[6] = (bf16)ry[i].z; t[7] = (bf16)ry[i].w;
      *(bf16x8*)&As[buf * 8192 + row * 64 + cs * 8] = t;
    }
  };

  auto compute = [&](int buf) {
    bf16* Ab = &As[buf * 8192];
    bf16* Bb = &Bs[buf * 8192];
#pragma unroll
    for (int h = 0; h < 2; h++) {
      bf16x8 af[4], bfv[4];
#pragma unroll
      for (int mi = 0; mi < 4; mi++) {
        int rr = wm + mi * 16 + qr;
        int cc = (h * 4 + quad) ^ (rr & 7);
        af[mi] = *(bf16x8*)&Ab[rr * 64 + cc * 8];
      }
#pragma unroll
      for (int ni = 0; ni < 4; ni++) {
        int rr = wn + ni * 16 + qr;
        int cc = (h * 4 + quad) ^ (rr & 7);
        bfv[ni] = *(bf16x8*)&Bb[rr * 64 + cc * 8];
      }
#pragma unroll
      for (int mi = 0; mi < 4; mi++)
#pragma unroll
        for (int ni = 0; ni < 4; ni++) acc[mi][ni] = MFMA(af[mi], bfv[ni], acc[mi][ni]);
    }
  };

  // prologue: stage tile 0 into buf 0
  issue(0, 0);
  writeA(0);
  __syncthreads();

  int cur = 0;
  for (int t = 0; t < 8; t++) {
    if (t < 7) issue((t + 1) * 64, cur ^ 1);
    compute(cur);
    if (t < 7) writeA(cur ^ 1);
    __syncthreads();
    cur ^= 1;
  }

  if (z == 2) {
    // V: transpose via LDS, then coalesced stores to Vtp[b*512+h][t]
    for (int ni = 0; ni < 4; ni++) {
      int hcol = wn + ni * 16 + qr;          // local h 0..127
      float bz = bias[n0 + hcol];
      for (int mi = 0; mi < 4; mi++) {
        int tl = wm + mi * 16 + quad * 4;    // local t base
        bf16 tmp[4];
        for (int r = 0; r < 4; r++) tmp[r] = (bf16)(acc[mi][ni][r] + bz);
        *(uint64_t*)&Ts[hcol * 136 + tl] = *(uint64_t*)tmp;
      }
    }
    __syncthreads();
    int bb = m0 >> 11, t0l = m0 & 2047;
    for (int i = 0; i < 8; i++) {
      int ch = i * 256 + tid;                // 2048 chunks: 128 h x 16
      int row = ch >> 4, c = ch & 15;
      *(bf16x8*)(Vtp + (size_t)(bb * 512 + n0 + row) * 2048 + t0l + c * 8) =
          *(bf16x8*)&Ts[row * 136 + c * 8];
    }
  } else {
    bf16* C = (z == 0) ? Qp : Kp;
    float sc = (z == 0) ? SCALE_L2E : 1.0f;
    for (int ni = 0; ni < 4; ni++) {
      int col = n0 + wn + ni * 16 + qr;
      float bz = bias[col];
      for (int mi = 0; mi < 4; mi++) {
        int rbase = m0 + wm + mi * 16 + quad * 4;
        for (int r = 0; r < 4; r++)
          C[(size_t)(rbase + r) * 512 + col] = (bf16)((acc[mi][ni][r] + bz) * sc);
      }
    }
  }
}

// ---------------------------------------------------------------------------
// Kernel 3: QK^T GEMM, BK=64, double-buffered prefetch, exp2 epilogue.
// Out: P[b][q][key] = exp2(s - M0) bf16; Lpart[slice][b*2048+q] row-partials.
// ---------------------------------------------------------------------------
__global__ __launch_bounds__(256, 2) void k_qk(const bf16* __restrict__ Qp,
                                               const bf16* __restrict__ Kp,
                                               bf16* __restrict__ P,
                                               float* __restrict__ Lpart) {
  __shared__ bf16 As[2][128 * 64];
  __shared__ bf16 Bs[2][128 * 64];
  int b = blockIdx.z;
  const bf16* A = Qp + (size_t)b * 2048 * 512;
  const bf16* B = Kp + (size_t)b * 2048 * 512;
  bf16* Pb = P + (size_t)b * 2048 * 2048;
  int m0 = blockIdx.x * 128, n0 = blockIdx.y * 128;
  int tid = threadIdx.x;
  int wave = tid >> 6, lane = tid & 63, qr = lane & 15, quad = lane >> 4;
  int wm = (wave >> 1) * 64, wn = (wave & 1) * 64;

  f32x4 acc[4][4];
  for (int mi = 0; mi < 4; mi++)
    for (int ni = 0; ni < 4; ni++) acc[mi][ni] = (f32x4){0.f, 0.f, 0.f, 0.f};

  auto stage = [&](int kk, int buf) {
#pragma unroll
    for (int i = 0; i < 4; i++) {
      int ch = i * 256 + tid, row = ch >> 3, c = ch & 7, cs = c ^ (row & 7);
      gload_lds16(A + (size_t)(m0 + row) * 512 + kk + cs * 8, &As[buf][ch * 8]);
      gload_lds16(B + (size_t)(n0 + row) * 512 + kk + cs * 8, &Bs[buf][ch * 8]);
    }
  };

  auto compute = [&](int buf) {
#pragma unroll
    for (int h = 0; h < 2; h++) {
      bf16x8 af[4], bfv[4];
#pragma unroll
      for (int mi = 0; mi < 4; mi++) {
        int rr = wm + mi * 16 + qr;
        int cc = (h * 4 + quad) ^ (rr & 7);
        af[mi] = *(bf16x8*)&As[buf][rr * 64 + cc * 8];
      }
#pragma unroll
      for (int ni = 0; ni < 4; ni++) {
        int rr = wn + ni * 16 + qr;
        int cc = (h * 4 + quad) ^ (rr & 7);
        bfv[ni] = *(bf16x8*)&Bs[buf][rr * 64 + cc * 8];
      }
#pragma unroll
      for (int mi = 0; mi < 4; mi++)
#pragma unroll
        for (int ni = 0; ni < 4; ni++) acc[mi][ni] = MFMA(af[mi], bfv[ni], acc[mi][ni]);
    }
  };

  stage(0, 0);
  __syncthreads();
  int cur = 0;
  for (int t = 0; t < 8; t++) {
    if (t < 7) stage((t + 1) * 64, cur ^ 1);
    compute(cur);
    __syncthreads();
    cur ^= 1;
  }

  int slice = blockIdx.y * 2 + (wave & 1);   // 32 slices of 64 keys each
  float* Lp = Lpart + (size_t)slice * 16384 + b * 2048;
  for (int mi = 0; mi < 4; mi++) {
    int rowb = m0 + wm + mi * 16 + quad * 4;
    for (int r = 0; r < 4; r++) {
      float s = 0.f;
      bf16* prow = Pb + (size_t)(rowb + r) * 2048 + n0 + wn + qr;
      for (int ni = 0; ni < 4; ni++) {
        float e = exp2f(acc[mi][ni][r] - M0);
        prow[ni * 16] = (bf16)e;
        s += e;
      }
      s += __shfl_xor(s, 1);
      s += __shfl_xor(s, 2);
      s += __shfl_xor(s, 4);
      s += __shfl_xor(s, 8);
      if (qr == 0) Lp[rowb + r] = s;
    }
  }
}

// ---------------------------------------------------------------------------
// Kernel 4: PV GEMM, 128x128, BK=64, 32-step K-loop, double-buffered prefetch.
// Folds the l-reduction: first 128 threads accumulate Linv in registers while
// the main loop runs; written to LDS (buffer reuse) after the final barrier.
// ---------------------------------------------------------------------------
__global__ __launch_bounds__(256, 2) void k_pv(const bf16* __restrict__ P,
                                               const bf16* __restrict__ Vtp,
                                               const float* __restrict__ Lpart,
                                               float* __restrict__ out) {
  __shared__ bf16 As[2][128 * 64];
  __shared__ bf16 Bs[2][128 * 64];
  int b = blockIdx.z;
  const bf16* A = P + (size_t)b * 2048 * 2048;
  const bf16* B = Vtp + (size_t)b * 512 * 2048;
  int m0 = blockIdx.x * 128, n0 = blockIdx.y * 128;   // m over q, n over h
  int tid = threadIdx.x;
  int wave = tid >> 6, lane = tid & 63, qr = lane & 15, quad = lane >> 4;
  int wm = (wave >> 1) * 64, wn = (wave & 1) * 64;

  float linv_own = 0.f;
  if (tid < 128) {
    float s = 0.f;
    for (int j = 0; j < 32; j++) s += Lpart[(size_t)j * 16384 + b * 2048 + m0 + tid];
    linv_own = 1.0f / s;
  }

  f32x4 acc[4][4];
  for (int mi = 0; mi < 4; mi++)
    for (int ni = 0; ni < 4; ni++) acc[mi][ni] = (f32x4){0.f, 0.f, 0.f, 0.f};

  auto stage = [&](int kk, int buf) {
#pragma unroll
    for (int i = 0; i < 4; i++) {
      int ch = i * 256 + tid, row = ch >> 3, c = ch & 7, cs = c ^ (row & 7);
      gload_lds16(A + (size_t)(m0 + row) * 2048 + kk + cs * 8, &As[buf][ch * 8]);
      gload_lds16(B + (size_t)(n0 + row) * 2048 + kk + cs * 8, &Bs[buf][ch * 8]);
    }
  };

  auto compute = [&](int buf) {
#pragma unroll
    for (int h = 0; h < 2; h++) {
      bf16x8 af[4], bfv[4];
#pragma unroll
      for (int mi = 0; mi < 4; mi++) {
        int rr = wm + mi * 16 + qr;
        int cc = (h * 4 + quad) ^ (rr & 7);
        af[mi] = *(bf16x8*)&As[buf][rr * 64 + cc * 8];
      }
#pragma unroll
      for (int ni = 0; ni < 4; ni++) {
        int rr = wn + ni * 16 + qr;
        int cc = (h * 4 + quad) ^ (rr & 7);
        bfv[ni] = *(bf16x8*)&Bs[buf][rr * 64 + cc * 8];
      }
#pragma unroll
      for (int mi = 0; mi < 4; mi++)
#pragma unroll
        for (int ni = 0; ni < 4; ni++) acc[mi][ni] = MFMA(af[mi], bfv[ni], acc[mi][ni]);
    }
  };

  stage(0, 0);
  __syncthreads();
  int cur = 0;
  for (int t = 0; t < 32; t++) {
    if (t < 31) stage((t + 1) * 64, cur ^ 1);
    compute(cur);
    __syncthreads();
    cur ^= 1;
  }

  // publish Linv via LDS reuse (main-loop buffers are dead past the last barrier)
  float* Linv_s = (float*)&As[0][0];
  if (tid < 128) Linv_s[tid] = linv_own;
  __syncthreads();

  for (int mi = 0; mi < 4; mi++) {
    int rowl = wm + mi * 16 + quad * 4;      // local q row base
    float linv[4];
    for (int r = 0; r < 4; r++) linv[r] = Linv_s[rowl + r];
    for (int ni = 0; ni < 4; ni++) {
      int col = n0 + wn + ni * 16 + qr;
      float* og = out + (size_t)(b * 2048 + m0 + rowl) * 512 + col;
      for (int r = 0; r < 4; r++) og[(size_t)r * 512] = acc[mi][ni][r] * linv[r];
    }
  }
}

// ---------------------------------------------------------------------------
extern "C" void kernel_launch(void* const* d_in, const int* in_sizes, int n_in,
                              void* d_out, int out_size, void* d_ws, size_t ws_size,
                              hipStream_t stream) {
  (void)in_sizes; (void)n_in; (void)out_size; (void)ws_size;
  const float* q  = (const float*)d_in[0];
  const float* k  = (const float*)d_in[1];
  const float* v  = (const float*)d_in[2];
  const float* Wq = (const float*)d_in[3];
  const float* bq = (const float*)d_in[4];
  const float* Wk = (const float*)d_in[5];
  const float* bk = (const float*)d_in[6];
  const float* Wv = (const float*)d_in[7];
  const float* bv = (const float*)d_in[8];
  float* out = (float*)d_out;

  char* ws = (char*)d_ws;
  bf16* Wt     = (bf16*)(ws);                 // 1,572,864 B
  bf16* Qp     = (bf16*)(ws + 1572864);       // 16 MiB
  bf16* Kp     = (bf16*)(ws + 18350080);      // 16 MiB
  bf16* Vtp    = (bf16*)(ws + 35127296);      // 16 MiB (written by k_proj z=2)
  bf16* P      = (bf16*)(ws + 51904512);      // 64 MiB
  float* Lpart = (float*)(ws + 119013376);    // 2 MiB  (total ~115.4 MiB)

  k_wtrans<<<dim3(16, 16, 3), dim3(32, 8, 1), 0, stream>>>(Wq, Wk, Wv, Wt);
  k_proj<<<dim3(128, 4, 3), 256, 0, stream>>>(q, k, v, Wt, bq, bk, bv, Qp, Kp, Vtp);
  k_qk<<<dim3(16, 16, 8), 256, 0, stream>>>(Qp, Kp, P, Lpart);
  k_pv<<<dim3(16, 4, 8), 256, 0, stream>>>(P, Vtp, Lpart, out);
}

// Round 2
// 267.744 us; speedup vs baseline: 1.0415x; 1.0415x over previous
//
#include <hip/hip_runtime.h>
#include <stdint.h>

typedef __bf16 bf16;
typedef bf16 bf16x8 __attribute__((ext_vector_type(8)));
typedef float f32x4 __attribute__((ext_vector_type(4)));

#define MFMA(a, b, c) __builtin_amdgcn_mfma_f32_16x16x32_bf16(a, b, c, 0, 0, 0)

// exp(0.25*s) = exp2(s * 0.25*log2(e)); scale folded into Qp at projection.
#define SCALE_L2E 0.3606737602222409f
#define M0 16.0f

#define WAITVM0 asm volatile("s_waitcnt vmcnt(0)" ::: "memory")
#define WAITLGKM0 asm volatile("s_waitcnt lgkmcnt(0)" ::: "memory")
#define SBAR __builtin_amdgcn_s_barrier()
#define SCHEDB __builtin_amdgcn_sched_barrier(0)
#define PRIO(x) __builtin_amdgcn_s_setprio(x)

__device__ __forceinline__ void gload_lds16(const void* g, void* l) {
  __builtin_amdgcn_global_load_lds(
      (const __attribute__((address_space(1))) uint32_t*)g,
      (__attribute__((address_space(3))) uint32_t*)l, 16, 0, 0);
}

// ---------------------------------------------------------------------------
// Kernel 1: Wt[z][n][k] = (bf16) W_z[k][n] — LDS-tiled transpose.
// ---------------------------------------------------------------------------
__global__ void k_wtrans(const float* __restrict__ Wq, const float* __restrict__ Wk,
                         const float* __restrict__ Wv, bf16* __restrict__ Wt) {
  __shared__ float tile[32][33];
  int x = threadIdx.x, y = threadIdx.y;
  int k0 = blockIdx.x * 32, n0 = blockIdx.y * 32, z = blockIdx.z;
  const float* W = (z == 0) ? Wq : (z == 1) ? Wk : Wv;
  for (int j = 0; j < 4; j++)
    tile[y + 8 * j][x] = W[(size_t)(k0 + y + 8 * j) * 512 + n0 + x];
  __syncthreads();
  bf16* o = Wt + (size_t)z * 262144;
  for (int j = 0; j < 4; j++)
    o[(size_t)(n0 + y + 8 * j) * 512 + k0 + x] = (bf16)tile[x][y + 8 * j];
}

// ---------------------------------------------------------------------------
// Kernel 2: projection GEMM (unchanged this round).
// ---------------------------------------------------------------------------
__global__ __launch_bounds__(256, 2) void k_proj(
    const float* __restrict__ q, const float* __restrict__ k, const float* __restrict__ v,
    const bf16* __restrict__ Wt, const float* __restrict__ bq, const float* __restrict__ bk,
    const float* __restrict__ bv, bf16* __restrict__ Qp, bf16* __restrict__ Kp,
    bf16* __restrict__ Vtp) {
  int z = blockIdx.z;
  const float* A = (z == 0) ? q : (z == 1) ? k : v;
  const float* bias = (z == 0) ? bq : (z == 1) ? bk : bv;
  const bf16* Bw = Wt + (size_t)z * 262144;

  int m0 = blockIdx.x * 128, n0 = blockIdx.y * 128;
  __shared__ __align__(16) char smem[65536];
  bf16* As = (bf16*)smem;            // 2 x (128 x 64), swizzled
  bf16* Bs = (bf16*)(smem + 32768);  // 2 x (128 x 64), swizzled
  bf16* Ts = (bf16*)smem;            // epilogue reuse: 128 x 136

  int tid = threadIdx.x;
  int wave = tid >> 6, lane = tid & 63, qr = lane & 15, quad = lane >> 4;
  int wm = (wave >> 1) * 64, wn = (wave & 1) * 64;

  f32x4 acc[4][4];
  for (int mi = 0; mi < 4; mi++)
    for (int ni = 0; ni < 4; ni++) acc[mi][ni] = (f32x4){0.f, 0.f, 0.f, 0.f};

  float4 rx[4], ry[4];

  auto issue = [&](int kk, int buf) {
#pragma unroll
    for (int i = 0; i < 4; i++) {
      int ch = i * 256 + tid, row = ch >> 3, c = ch & 7;
      const float4* src = (const float4*)(A + (size_t)(m0 + row) * 512 + kk + c * 8);
      rx[i] = src[0];
      ry[i] = src[1];
    }
#pragma unroll
    for (int i = 0; i < 4; i++) {
      int ch = i * 256 + tid, row = ch >> 3, c = ch & 7, cs = c ^ (row & 7);
      gload_lds16(Bw + (size_t)(n0 + row) * 512 + kk + cs * 8, &Bs[buf * 8192 + ch * 8]);
    }
  };

  auto writeA = [&](int buf) {
#pragma unroll
    for (int i = 0; i < 4; i++) {
      int ch = i * 256 + tid, row = ch >> 3, c = ch & 7, cs = c ^ (row & 7);
      bf16x8 t;
      t[0] = (bf16)rx[i].x; t[1] = (bf16)rx[i].y; t[2] = (bf16)rx[i].z; t[3] = (bf16)rx[i].w;
      t[4] = (bf16)ry[i].x; t[5] = (bf16)ry[i].y; t[6] = (bf16)ry[i].z; t[7] = (bf16)ry[i].w;
      *(bf16x8*)&As[buf * 8192 + row * 64 + cs * 8] = t;
    }
  };

  auto compute = [&](int buf) {
    bf16* Ab = &As[buf * 8192];
    bf16* Bb = &Bs[buf * 8192];
#pragma unroll
    for (int h = 0; h < 2; h++) {
      bf16x8 af[4], bfv[4];
#pragma unroll
      for (int mi = 0; mi < 4; mi++) {
        int rr = wm + mi * 16 + qr;
        int cc = (h * 4 + quad) ^ (rr & 7);
        af[mi] = *(bf16x8*)&Ab[rr * 64 + cc * 8];
      }
#pragma unroll
      for (int ni = 0; ni < 4; ni++) {
        int rr = wn + ni * 16 + qr;
        int cc = (h * 4 + quad) ^ (rr & 7);
        bfv[ni] = *(bf16x8*)&Bb[rr * 64 + cc * 8];
      }
#pragma unroll
      for (int mi = 0; mi < 4; mi++)
#pragma unroll
        for (int ni = 0; ni < 4; ni++) acc[mi][ni] = MFMA(af[mi], bfv[ni], acc[mi][ni]);
    }
  };

  issue(0, 0);
  writeA(0);
  __syncthreads();

  int cur = 0;
  for (int t = 0; t < 8; t++) {
    if (t < 7) issue((t + 1) * 64, cur ^ 1);
    compute(cur);
    if (t < 7) writeA(cur ^ 1);
    __syncthreads();
    cur ^= 1;
  }

  if (z == 2) {
    for (int ni = 0; ni < 4; ni++) {
      int hcol = wn + ni * 16 + qr;
      float bz = bias[n0 + hcol];
      for (int mi = 0; mi < 4; mi++) {
        int tl = wm + mi * 16 + quad * 4;
        bf16 tmp[4];
        for (int r = 0; r < 4; r++) tmp[r] = (bf16)(acc[mi][ni][r] + bz);
        *(uint64_t*)&Ts[hcol * 136 + tl] = *(uint64_t*)tmp;
      }
    }
    __syncthreads();
    int bb = m0 >> 11, t0l = m0 & 2047;
    for (int i = 0; i < 8; i++) {
      int ch = i * 256 + tid;
      int row = ch >> 4, c = ch & 15;
      *(bf16x8*)(Vtp + (size_t)(bb * 512 + n0 + row) * 2048 + t0l + c * 8) =
          *(bf16x8*)&Ts[row * 136 + c * 8];
    }
  } else {
    bf16* C = (z == 0) ? Qp : Kp;
    float sc = (z == 0) ? SCALE_L2E : 1.0f;
    for (int ni = 0; ni < 4; ni++) {
      int col = n0 + wn + ni * 16 + qr;
      float bz = bias[col];
      for (int mi = 0; mi < 4; mi++) {
        int rbase = m0 + wm + mi * 16 + quad * 4;
        for (int r = 0; r < 4; r++)
          C[(size_t)(rbase + r) * 512 + col] = (bf16)((acc[mi][ni][r] + bz) * sc);
      }
    }
  }
}

// ---------------------------------------------------------------------------
// Kernel 3: QK^T GEMM — 256x256 tile, BK=64, 8 waves (2M x 4N), phase-split
// schedule: per K-tile, 2 compute phases of 32 MFMA each (mi-halves), B frags
// held in registers across both. Staging front-loaded at phase 1 (8 gloads),
// drained by a single vmcnt(0) ~1.5 phases later. Raw barriers + setprio.
// grid (8,8,8), block 512. LDS 128 KiB -> 1 block/CU, 8 waves.
// ---------------------------------------------------------------------------
__global__ __launch_bounds__(512, 1) void k_qk(const bf16* __restrict__ Qp,
                                               const bf16* __restrict__ Kp,
                                               bf16* __restrict__ P,
                                               float* __restrict__ Lpart) {
  __shared__ __align__(16) bf16 S[65536];  // A: [0,32768) 2 slots; B: [32768,65536)
  int b = blockIdx.z;
  const bf16* A = Qp + (size_t)b * 2048 * 512;
  const bf16* B = Kp + (size_t)b * 2048 * 512;
  bf16* Pb = P + (size_t)b * 2048 * 2048;
  int m0 = blockIdx.x * 256, n0 = blockIdx.y * 256;
  int tid = threadIdx.x;
  int wave = tid >> 6, lane = tid & 63, qr = lane & 15, quad = lane >> 4;
  int wm = wave >> 2, wn = wave & 3;  // 2M x 4N; wave tile 128 x 64

  f32x4 acc[8][4];
  for (int mi = 0; mi < 8; mi++)
    for (int ni = 0; ni < 4; ni++) acc[mi][ni] = (f32x4){0.f, 0.f, 0.f, 0.f};

  auto stage = [&](int t, int s) {
    int kk = t * 64;
    bf16* As_ = S + s * 16384;
    bf16* Bs_ = S + 32768 + s * 16384;
#pragma unroll
    for (int j = 0; j < 4; j++) {
      int ch = j * 512 + tid, row = ch >> 3, c = ch & 7, cs = c ^ (row & 7);
      gload_lds16(A + (size_t)(m0 + row) * 512 + kk + cs * 8, As_ + ch * 8);
    }
#pragma unroll
    for (int j = 0; j < 4; j++) {
      int ch = j * 512 + tid, row = ch >> 3, c = ch & 7, cs = c ^ (row & 7);
      gload_lds16(B + (size_t)(n0 + row) * 512 + kk + cs * 8, Bs_ + ch * 8);
    }
  };

  stage(0, 0);
  WAITVM0;
  SBAR;

  for (int t = 0; t < 8; t++) {
    int cur = t & 1;
    bf16* As_ = S + cur * 16384;
    bf16* Bs_ = S + 32768 + cur * 16384;

    // ---- phase 1: stage t+1 (8 gloads), read A-lo (8) + all B (8), 32 MFMA
    if (t < 7) stage(t + 1, cur ^ 1);
    bf16x8 aF[4][2], bF[4][2];
#pragma unroll
    for (int mi = 0; mi < 4; mi++)
#pragma unroll
      for (int kk = 0; kk < 2; kk++) {
        int row = wm * 128 + mi * 16 + qr;
        aF[mi][kk] = *(bf16x8*)&As_[row * 64 + ((kk * 4 + quad) ^ (row & 7)) * 8];
      }
#pragma unroll
    for (int ni = 0; ni < 4; ni++)
#pragma unroll
      for (int kk = 0; kk < 2; kk++) {
        int row = wn * 64 + ni * 16 + qr;
        bF[ni][kk] = *(bf16x8*)&Bs_[row * 64 + ((kk * 4 + quad) ^ (row & 7)) * 8];
      }
    SBAR;
    WAITLGKM0;
    SCHEDB;
    PRIO(1);
#pragma unroll
    for (int kk = 0; kk < 2; kk++)
#pragma unroll
      for (int mi = 0; mi < 4; mi++)
#pragma unroll
        for (int ni = 0; ni < 4; ni++)
          acc[mi][ni] = MFMA(aF[mi][kk], bF[ni][kk], acc[mi][ni]);
    PRIO(0);
    SBAR;

    // ---- phase 2: read A-hi (8), 32 MFMA, drain stage loads, barrier
#pragma unroll
    for (int mi = 0; mi < 4; mi++)
#pragma unroll
      for (int kk = 0; kk < 2; kk++) {
        int row = wm * 128 + 64 + mi * 16 + qr;
        aF[mi][kk] = *(bf16x8*)&As_[row * 64 + ((kk * 4 + quad) ^ (row & 7)) * 8];
      }
    SBAR;
    WAITLGKM0;
    SCHEDB;
    PRIO(1);
#pragma unroll
    for (int kk = 0; kk < 2; kk++)
#pragma unroll
      for (int mi = 0; mi < 4; mi++)
#pragma unroll
        for (int ni = 0; ni < 4; ni++)
          acc[4 + mi][ni] = MFMA(aF[mi][kk], bF[ni][kk], acc[4 + mi][ni]);
    PRIO(0);
    WAITVM0;
    SBAR;
  }

  int slice = blockIdx.y * 4 + wn;  // 32 slices of 64 keys
  float* Lp = Lpart + (size_t)slice * 16384 + b * 2048;
#pragma unroll
  for (int mi = 0; mi < 8; mi++) {
    int rowb = m0 + wm * 128 + mi * 16 + quad * 4;
#pragma unroll
    for (int r = 0; r < 4; r++) {
      float s = 0.f;
      bf16* prow = Pb + (size_t)(rowb + r) * 2048 + n0 + wn * 64 + qr;
#pragma unroll
      for (int ni = 0; ni < 4; ni++) {
        float e = exp2f(acc[mi][ni][r] - M0);
        prow[ni * 16] = (bf16)e;
        s += e;
      }
      s += __shfl_xor(s, 1);
      s += __shfl_xor(s, 2);
      s += __shfl_xor(s, 4);
      s += __shfl_xor(s, 8);
      if (qr == 0) Lp[rowb + r] = s;
    }
  }
}

// ---------------------------------------------------------------------------
// Kernel 4: PV GEMM — 256x128 tile, BK=64, 8 waves (4M x 2N), same phase-split
// schedule (2 phases/K-tile, 16 MFMA each, B in regs). 32 K-tiles.
// grid (8,4,8) = 256 blocks (1/CU), block 512. LDS 96 KiB.
// ---------------------------------------------------------------------------
__global__ __launch_bounds__(512, 1) void k_pv(const bf16* __restrict__ P,
                                               const bf16* __restrict__ Vtp,
                                               const float* __restrict__ Lpart,
                                               float* __restrict__ out) {
  __shared__ __align__(16) bf16 S[49152];  // A: [0,32768) 2 slots; B: [32768,49152) 2 slots
  int b = blockIdx.z;
  const bf16* A = P + (size_t)b * 2048 * 2048;
  const bf16* B = Vtp + (size_t)b * 512 * 2048;
  int m0 = blockIdx.x * 256, n0 = blockIdx.y * 128;  // m over q, n over h
  int tid = threadIdx.x;
  int wave = tid >> 6, lane = tid & 63, qr = lane & 15, quad = lane >> 4;
  int wmi = wave >> 1, wni = wave & 1;  // 4M x 2N; wave tile 64 x 64

  float linv_own = 0.f;
  if (tid < 256) {
    float s = 0.f;
    for (int j = 0; j < 32; j++) s += Lpart[(size_t)j * 16384 + b * 2048 + m0 + tid];
    linv_own = 1.0f / s;
  }

  f32x4 acc[4][4];
  for (int mi = 0; mi < 4; mi++)
    for (int ni = 0; ni < 4; ni++) acc[mi][ni] = (f32x4){0.f, 0.f, 0.f, 0.f};

  auto stage = [&](int t, int s) {
    int kk = t * 64;
    bf16* As_ = S + s * 16384;
    bf16* Bs_ = S + 32768 + s * 8192;
#pragma unroll
    for (int j = 0; j < 4; j++) {
      int ch = j * 512 + tid, row = ch >> 3, c = ch & 7, cs = c ^ (row & 7);
      gload_lds16(A + (size_t)(m0 + row) * 2048 + kk + cs * 8, As_ + ch * 8);
    }
#pragma unroll
    for (int j = 0; j < 2; j++) {
      int ch = j * 512 + tid, row = ch >> 3, c = ch & 7, cs = c ^ (row & 7);
      gload_lds16(B + (size_t)(n0 + row) * 2048 + kk + cs * 8, Bs_ + ch * 8);
    }
  };

  stage(0, 0);
  WAITVM0;
  SBAR;

  for (int t = 0; t < 32; t++) {
    int cur = t & 1;
    bf16* As_ = S + cur * 16384;
    bf16* Bs_ = S + 32768 + cur * 8192;

    // ---- phase 1: stage t+1 (6 gloads), read A mi0-1 (4) + all B (8), 16 MFMA
    if (t < 31) stage(t + 1, cur ^ 1);
    bf16x8 aF[2][2], bF[4][2];
#pragma unroll
    for (int mi = 0; mi < 2; mi++)
#pragma unroll
      for (int kk = 0; kk < 2; kk++) {
        int row = wmi * 64 + mi * 16 + qr;
        aF[mi][kk] = *(bf16x8*)&As_[row * 64 + ((kk * 4 + quad) ^ (row & 7)) * 8];
      }
#pragma unroll
    for (int ni = 0; ni < 4; ni++)
#pragma unroll
      for (int kk = 0; kk < 2; kk++) {
        int row = wni * 64 + ni * 16 + qr;
        bF[ni][kk] = *(bf16x8*)&Bs_[row * 64 + ((kk * 4 + quad) ^ (row & 7)) * 8];
      }
    SBAR;
    WAITLGKM0;
    SCHEDB;
    PRIO(1);
#pragma unroll
    for (int kk = 0; kk < 2; kk++)
#pragma unroll
      for (int mi = 0; mi < 2; mi++)
#pragma unroll
        for (int ni = 0; ni < 4; ni++)
          acc[mi][ni] = MFMA(aF[mi][kk], bF[ni][kk], acc[mi][ni]);
    PRIO(0);
    SBAR;

    // ---- phase 2: read A mi2-3 (4), 16 MFMA, drain, barrier
#pragma unroll
    for (int mi = 0; mi < 2; mi++)
#pragma unroll
      for (int kk = 0; kk < 2; kk++) {
        int row = wmi * 64 + 32 + mi * 16 + qr;
        aF[mi][kk] = *(bf16x8*)&As_[row * 64 + ((kk * 4 + quad) ^ (row & 7)) * 8];
      }
    SBAR;
    WAITLGKM0;
    SCHEDB;
    PRIO(1);
#pragma unroll
    for (int kk = 0; kk < 2; kk++)
#pragma unroll
      for (int mi = 0; mi < 2; mi++)
#pragma unroll
        for (int ni = 0; ni < 4; ni++)
          acc[2 + mi][ni] = MFMA(aF[mi][kk], bF[ni][kk], acc[2 + mi][ni]);
    PRIO(0);
    WAITVM0;
    SBAR;
  }

  // publish Linv via LDS reuse (all staging/reads retired past last barrier)
  float* Linv_s = (float*)S;
  if (tid < 256) Linv_s[tid] = linv_own;
  SBAR;

#pragma unroll
  for (int mi = 0; mi < 4; mi++) {
    int rowl = wmi * 64 + mi * 16 + quad * 4;  // local q row base (0..255)
    float linv[4];
    for (int r = 0; r < 4; r++) linv[r] = Linv_s[rowl + r];
#pragma unroll
    for (int ni = 0; ni < 4; ni++) {
      int col = n0 + wni * 64 + ni * 16 + qr;
      float* og = out + (size_t)(b * 2048 + m0 + rowl) * 512 + col;
      for (int r = 0; r < 4; r++) og[(size_t)r * 512] = acc[mi][ni][r] * linv[r];
    }
  }
}

// ---------------------------------------------------------------------------
extern "C" void kernel_launch(void* const* d_in, const int* in_sizes, int n_in,
                              void* d_out, int out_size, void* d_ws, size_t ws_size,
                              hipStream_t stream) {
  (void)in_sizes; (void)n_in; (void)out_size; (void)ws_size;
  const float* q  = (const float*)d_in[0];
  const float* k  = (const float*)d_in[1];
  const float* v  = (const float*)d_in[2];
  const float* Wq = (const float*)d_in[3];
  const float* bq = (const float*)d_in[4];
  const float* Wk = (const float*)d_in[5];
  const float* bk = (const float*)d_in[6];
  const float* Wv = (const float*)d_in[7];
  const float* bv = (const float*)d_in[8];
  float* out = (float*)d_out;

  char* ws = (char*)d_ws;
  bf16* Wt     = (bf16*)(ws);                 // 1,572,864 B
  bf16* Qp     = (bf16*)(ws + 1572864);       // 16 MiB
  bf16* Kp     = (bf16*)(ws + 18350080);      // 16 MiB
  bf16* Vtp    = (bf16*)(ws + 35127296);      // 16 MiB (written by k_proj z=2)
  bf16* P      = (bf16*)(ws + 51904512);      // 64 MiB
  float* Lpart = (float*)(ws + 119013376);    // 2 MiB  (total ~115.4 MiB)

  k_wtrans<<<dim3(16, 16, 3), dim3(32, 8, 1), 0, stream>>>(Wq, Wk, Wv, Wt);
  k_proj<<<dim3(128, 4, 3), 256, 0, stream>>>(q, k, v, Wt, bq, bk, bv, Qp, Kp, Vtp);
  k_qk<<<dim3(8, 8, 8), 512, 0, stream>>>(Qp, Kp, P, Lpart);
  k_pv<<<dim3(8, 4, 8), 512, 0, stream>>>(P, Vtp, Lpart, out);
}

// Round 4
// 262.288 us; speedup vs baseline: 1.0631x; 1.0208x over previous
//
#include <hip/hip_runtime.h>
#include <stdint.h>

typedef __bf16 bf16;
typedef bf16 bf16x8 __attribute__((ext_vector_type(8)));
typedef float f32x4 __attribute__((ext_vector_type(4)));

#define MFMA(a, b, c) __builtin_amdgcn_mfma_f32_16x16x32_bf16(a, b, c, 0, 0, 0)

// exp(0.25*s) = exp2(s * 0.25*log2(e)); scale folded into Qp at projection.
#define SCALE_L2E 0.3606737602222409f
#define M0 16.0f

#define WAITVM(N) asm volatile("s_waitcnt vmcnt(" #N ")" ::: "memory")
#define WAITLGKM0 asm volatile("s_waitcnt lgkmcnt(0)" ::: "memory")
#define SBAR __builtin_amdgcn_s_barrier()
#define SCHEDB __builtin_amdgcn_sched_barrier(0)
#define PRIO(x) __builtin_amdgcn_s_setprio(x)

__device__ __forceinline__ void gload_lds16(const void* g, void* l) {
  __builtin_amdgcn_global_load_lds(
      (const __attribute__((address_space(1))) uint32_t*)g,
      (__attribute__((address_space(3))) uint32_t*)l, 16, 0, 0);
}

// ---------------------------------------------------------------------------
// Kernel 1: Wt[z][n][k] = (bf16) W_z[k][n] — LDS-tiled transpose.
// ---------------------------------------------------------------------------
__global__ void k_wtrans(const float* __restrict__ Wq, const float* __restrict__ Wk,
                         const float* __restrict__ Wv, bf16* __restrict__ Wt) {
  __shared__ float tile[32][33];
  int x = threadIdx.x, y = threadIdx.y;
  int k0 = blockIdx.x * 32, n0 = blockIdx.y * 32, z = blockIdx.z;
  const float* W = (z == 0) ? Wq : (z == 1) ? Wk : Wv;
  for (int j = 0; j < 4; j++)
    tile[y + 8 * j][x] = W[(size_t)(k0 + y + 8 * j) * 512 + n0 + x];
  __syncthreads();
  bf16* o = Wt + (size_t)z * 262144;
  for (int j = 0; j < 4; j++)
    o[(size_t)(n0 + y + 8 * j) * 512 + k0 + x] = (bf16)tile[x][y + 8 * j];
}

// ---------------------------------------------------------------------------
// Kernel 2: projection GEMM, BK=64, double-buffered, COUNTED vmcnt.
// Queue at tile t's WAITVM(12): [B(t)x4, A(t+1)x8, B(t+1)x4] -> drains B(t)
// only. SBAR after the wait makes other waves' B(t) gloads visible (race fix
// vs round 3). writeA's compiler-counted wait drains A(t+1), leaves B(t+1).
// SCHEDB pins in issue() keep the queue order the arithmetic assumes.
// ---------------------------------------------------------------------------
__global__ __launch_bounds__(256, 2) void k_proj(
    const float* __restrict__ q, const float* __restrict__ k, const float* __restrict__ v,
    const bf16* __restrict__ Wt, const float* __restrict__ bq, const float* __restrict__ bk,
    const float* __restrict__ bv, bf16* __restrict__ Qp, bf16* __restrict__ Kp,
    bf16* __restrict__ Vtp) {
  int z = blockIdx.z;
  const float* A = (z == 0) ? q : (z == 1) ? k : v;
  const float* bias = (z == 0) ? bq : (z == 1) ? bk : bv;
  const bf16* Bw = Wt + (size_t)z * 262144;

  int m0 = blockIdx.x * 128, n0 = blockIdx.y * 128;
  __shared__ __align__(16) char smem[65536];
  bf16* As = (bf16*)smem;            // 2 x (128 x 64), swizzled
  bf16* Bs = (bf16*)(smem + 32768);  // 2 x (128 x 64), swizzled
  bf16* Ts = (bf16*)smem;            // epilogue reuse: 128 x 136

  int tid = threadIdx.x;
  int wave = tid >> 6, lane = tid & 63, qr = lane & 15, quad = lane >> 4;
  int wm = (wave >> 1) * 64, wn = (wave & 1) * 64;

  f32x4 acc[4][4];
  for (int mi = 0; mi < 4; mi++)
    for (int ni = 0; ni < 4; ni++) acc[mi][ni] = (f32x4){0.f, 0.f, 0.f, 0.f};

  float4 rx[4], ry[4];

  auto issue = [&](int kk, int buf) {
#pragma unroll
    for (int i = 0; i < 4; i++) {
      int ch = i * 256 + tid, row = ch >> 3, c = ch & 7;
      const float4* src = (const float4*)(A + (size_t)(m0 + row) * 512 + kk + c * 8);
      rx[i] = src[0];
      ry[i] = src[1];
    }
    SCHEDB;  // pin: A f32 loads issued before B gloads
#pragma unroll
    for (int i = 0; i < 4; i++) {
      int ch = i * 256 + tid, row = ch >> 3, c = ch & 7, cs = c ^ (row & 7);
      gload_lds16(Bw + (size_t)(n0 + row) * 512 + kk + cs * 8, &Bs[buf * 8192 + ch * 8]);
    }
    SCHEDB;  // pin: nothing sinks below the B gloads
  };

  auto writeA = [&](int buf) {
#pragma unroll
    for (int i = 0; i < 4; i++) {
      int ch = i * 256 + tid, row = ch >> 3, c = ch & 7, cs = c ^ (row & 7);
      bf16x8 t;
      t[0] = (bf16)rx[i].x; t[1] = (bf16)rx[i].y; t[2] = (bf16)rx[i].z; t[3] = (bf16)rx[i].w;
      t[4] = (bf16)ry[i].x; t[5] = (bf16)ry[i].y; t[6] = (bf16)ry[i].z; t[7] = (bf16)ry[i].w;
      *(bf16x8*)&As[buf * 8192 + row * 64 + cs * 8] = t;
    }
  };

  auto compute = [&](int buf) {
    bf16* Ab = &As[buf * 8192];
    bf16* Bb = &Bs[buf * 8192];
#pragma unroll
    for (int h = 0; h < 2; h++) {
      bf16x8 af[4], bfv[4];
#pragma unroll
      for (int mi = 0; mi < 4; mi++) {
        int rr = wm + mi * 16 + qr;
        int cc = (h * 4 + quad) ^ (rr & 7);
        af[mi] = *(bf16x8*)&Ab[rr * 64 + cc * 8];
      }
#pragma unroll
      for (int ni = 0; ni < 4; ni++) {
        int rr = wn + ni * 16 + qr;
        int cc = (h * 4 + quad) ^ (rr & 7);
        bfv[ni] = *(bf16x8*)&Bb[rr * 64 + cc * 8];
      }
#pragma unroll
      for (int mi = 0; mi < 4; mi++)
#pragma unroll
        for (int ni = 0; ni < 4; ni++) acc[mi][ni] = MFMA(af[mi], bfv[ni], acc[mi][ni]);
    }
  };

  issue(0, 0);
  writeA(0);          // waits A(0); B(0) stays in flight
  WAITLGKM0;
  SBAR;

  for (int t = 0; t < 8; t++) {
    int cur = t & 1;
    if (t < 7) issue((t + 1) * 64, cur ^ 1);  // queue: B(t)x4, A(t+1)x8, B(t+1)x4
    if (t < 7) { WAITVM(12); } else { WAITVM(0); }  // drain B(t) only
    SBAR;   // make ALL waves' B(t) visible before reading Bs (race fix)
    SCHEDB;
    compute(cur);
    if (t < 7) writeA(cur ^ 1);  // compiler waits A(t+1); B(t+1) still flying
    WAITLGKM0;
    SBAR;
  }

  if (z == 2) {
    for (int ni = 0; ni < 4; ni++) {
      int hcol = wn + ni * 16 + qr;
      float bz = bias[n0 + hcol];
      for (int mi = 0; mi < 4; mi++) {
        int tl = wm + mi * 16 + quad * 4;
        bf16 tmp[4];
        for (int r = 0; r < 4; r++) tmp[r] = (bf16)(acc[mi][ni][r] + bz);
        *(uint64_t*)&Ts[hcol * 136 + tl] = *(uint64_t*)tmp;
      }
    }
    __syncthreads();
    int bb = m0 >> 11, t0l = m0 & 2047;
    for (int i = 0; i < 8; i++) {
      int ch = i * 256 + tid;
      int row = ch >> 4, c = ch & 15;
      *(bf16x8*)(Vtp + (size_t)(bb * 512 + n0 + row) * 2048 + t0l + c * 8) =
          *(bf16x8*)&Ts[row * 136 + c * 8];
    }
  } else {
    bf16* C = (z == 0) ? Qp : Kp;
    float sc = (z == 0) ? SCALE_L2E : 1.0f;
    for (int ni = 0; ni < 4; ni++) {
      int col = n0 + wn + ni * 16 + qr;
      float bz = bias[col];
      for (int mi = 0; mi < 4; mi++) {
        int rbase = m0 + wm + mi * 16 + quad * 4;
        for (int r = 0; r < 4; r++)
          C[(size_t)(rbase + r) * 512 + col] = (bf16)((acc[mi][ni][r] + bz) * sc);
      }
    }
  }
}

// ---------------------------------------------------------------------------
// Kernel 3: QK^T GEMM — 256x256, BK=64, 8 waves (2M x 4N), COUNTED vmcnt.
// 2 tiles prefetched. Per tile: phase1 waits vmcnt(10) (keeps t's A-hi + all
// of t+1 in flight), phase2 waits vmcnt(8); stage(t+2) after read-complete
// barrier. vmcnt drains to 0 only at the final tile.
// Stage issue order per tile: B x4, A-lo x2 (j=0,2), A-hi x2 (j=1,3).
// ---------------------------------------------------------------------------
__global__ __launch_bounds__(512, 1) void k_qk(const bf16* __restrict__ Qp,
                                               const bf16* __restrict__ Kp,
                                               bf16* __restrict__ P,
                                               float* __restrict__ Lpart) {
  __shared__ __align__(16) bf16 S[65536];  // A: [0,32768) 2 slots; B: [32768,65536)
  int b = blockIdx.z;
  const bf16* A = Qp + (size_t)b * 2048 * 512;
  const bf16* B = Kp + (size_t)b * 2048 * 512;
  bf16* Pb = P + (size_t)b * 2048 * 2048;
  int m0 = blockIdx.x * 256, n0 = blockIdx.y * 256;
  int tid = threadIdx.x;
  int wave = tid >> 6, lane = tid & 63, qr = lane & 15, quad = lane >> 4;
  int wm = wave >> 2, wn = wave & 3;  // 2M x 4N; wave tile 128 x 64

  f32x4 acc[8][4];
  for (int mi = 0; mi < 8; mi++)
    for (int ni = 0; ni < 4; ni++) acc[mi][ni] = (f32x4){0.f, 0.f, 0.f, 0.f};

  auto stageAj = [&](int t, int s, int j) {
    int kk = t * 64;
    bf16* As_ = S + s * 16384;
    int ch = j * 512 + tid, row = ch >> 3, c = ch & 7, cs = c ^ (row & 7);
    gload_lds16(A + (size_t)(m0 + row) * 512 + kk + cs * 8, As_ + ch * 8);
  };
  auto stage = [&](int t, int s) {
    int kk = t * 64;
    bf16* Bs_ = S + 32768 + s * 16384;
#pragma unroll
    for (int j = 0; j < 4; j++) {
      int ch = j * 512 + tid, row = ch >> 3, c = ch & 7, cs = c ^ (row & 7);
      gload_lds16(B + (size_t)(n0 + row) * 512 + kk + cs * 8, Bs_ + ch * 8);
    }
    stageAj(t, s, 0);  // rows   0..63  (phase-1, wm=0)
    stageAj(t, s, 2);  // rows 128..191 (phase-1, wm=1)
    stageAj(t, s, 1);  // rows  64..127 (phase-2, wm=0)
    stageAj(t, s, 3);  // rows 192..255 (phase-2, wm=1)
  };

  stage(0, 0);
  stage(1, 1);  // 16 loads/thread in flight

  for (int t = 0; t < 8; t++) {
    int cur = t & 1;
    bf16* As_ = S + cur * 16384;
    bf16* Bs_ = S + 32768 + cur * 16384;

    // ---- phase 1: drain t's B + A-lo only; read A-lo + all B; 32 MFMA
    if (t < 7) { WAITVM(10); } else { WAITVM(2); }
    SBAR;
    bf16x8 aF[4][2], bF[4][2];
#pragma unroll
    for (int mi = 0; mi < 4; mi++)
#pragma unroll
      for (int kk = 0; kk < 2; kk++) {
        int row = wm * 128 + mi * 16 + qr;
        aF[mi][kk] = *(bf16x8*)&As_[row * 64 + ((kk * 4 + quad) ^ (row & 7)) * 8];
      }
#pragma unroll
    for (int ni = 0; ni < 4; ni++)
#pragma unroll
      for (int kk = 0; kk < 2; kk++) {
        int row = wn * 64 + ni * 16 + qr;
        bF[ni][kk] = *(bf16x8*)&Bs_[row * 64 + ((kk * 4 + quad) ^ (row & 7)) * 8];
      }
    WAITLGKM0;
    SCHEDB;
    PRIO(1);
#pragma unroll
    for (int kk = 0; kk < 2; kk++)
#pragma unroll
      for (int mi = 0; mi < 4; mi++)
#pragma unroll
        for (int ni = 0; ni < 4; ni++)
          acc[mi][ni] = MFMA(aF[mi][kk], bF[ni][kk], acc[mi][ni]);
    PRIO(0);

    // ---- phase 2: drain t's A-hi; read A-hi; restage t+2; 32 MFMA
    if (t < 7) { WAITVM(8); } else { WAITVM(0); }
    SBAR;
#pragma unroll
    for (int mi = 0; mi < 4; mi++)
#pragma unroll
      for (int kk = 0; kk < 2; kk++) {
        int row = wm * 128 + 64 + mi * 16 + qr;
        aF[mi][kk] = *(bf16x8*)&As_[row * 64 + ((kk * 4 + quad) ^ (row & 7)) * 8];
      }
    WAITLGKM0;
    SBAR;  // all waves done reading buf cur -> safe to overwrite
    if (t < 6) stage(t + 2, cur);
    SCHEDB;
    PRIO(1);
#pragma unroll
    for (int kk = 0; kk < 2; kk++)
#pragma unroll
      for (int mi = 0; mi < 4; mi++)
#pragma unroll
        for (int ni = 0; ni < 4; ni++)
          acc[4 + mi][ni] = MFMA(aF[mi][kk], bF[ni][kk], acc[4 + mi][ni]);
    PRIO(0);
  }

  int slice = blockIdx.y * 4 + wn;  // 32 slices of 64 keys
  float* Lp = Lpart + (size_t)slice * 16384 + b * 2048;
#pragma unroll
  for (int mi = 0; mi < 8; mi++) {
    int rowb = m0 + wm * 128 + mi * 16 + quad * 4;
#pragma unroll
    for (int r = 0; r < 4; r++) {
      float s = 0.f;
      bf16* prow = Pb + (size_t)(rowb + r) * 2048 + n0 + wn * 64 + qr;
#pragma unroll
      for (int ni = 0; ni < 4; ni++) {
        float e = exp2f(acc[mi][ni][r] - M0);
        prow[ni * 16] = (bf16)e;
        s += e;
      }
      s += __shfl_xor(s, 1);
      s += __shfl_xor(s, 2);
      s += __shfl_xor(s, 4);
      s += __shfl_xor(s, 8);
      if (qr == 0) Lp[rowb + r] = s;
    }
  }
}

// ---------------------------------------------------------------------------
// Kernel 4: PV GEMM — 256x128, BK=64, 8 waves (4M x 2N), COUNTED vmcnt.
// Single compute phase per tile, vmcnt(6) keeps tile t+1's 6 loads in flight;
// stage(t+2) after the read-complete barrier. 32 K-tiles (long steady state).
// ---------------------------------------------------------------------------
__global__ __launch_bounds__(512, 1) void k_pv(const bf16* __restrict__ P,
                                               const bf16* __restrict__ Vtp,
                                               const float* __restrict__ Lpart,
                                               float* __restrict__ out) {
  __shared__ __align__(16) bf16 S[49152];  // A: [0,32768) 2 slots; B: [32768,49152) 2 slots
  int b = blockIdx.z;
  const bf16* A = P + (size_t)b * 2048 * 2048;
  const bf16* B = Vtp + (size_t)b * 512 * 2048;
  int m0 = blockIdx.x * 256, n0 = blockIdx.y * 128;  // m over q, n over h
  int tid = threadIdx.x;
  int wave = tid >> 6, lane = tid & 63, qr = lane & 15, quad = lane >> 4;
  int wmi = wave >> 1, wni = wave & 1;  // 4M x 2N; wave tile 64 x 64

  float linv_own = 0.f;
  if (tid < 256) {
    float s = 0.f;
    for (int j = 0; j < 32; j++) s += Lpart[(size_t)j * 16384 + b * 2048 + m0 + tid];
    linv_own = 1.0f / s;
  }

  f32x4 acc[4][4];
  for (int mi = 0; mi < 4; mi++)
    for (int ni = 0; ni < 4; ni++) acc[mi][ni] = (f32x4){0.f, 0.f, 0.f, 0.f};

  auto stage = [&](int t, int s) {
    int kk = t * 64;
    bf16* As_ = S + s * 16384;
    bf16* Bs_ = S + 32768 + s * 8192;
#pragma unroll
    for (int j = 0; j < 4; j++) {
      int ch = j * 512 + tid, row = ch >> 3, c = ch & 7, cs = c ^ (row & 7);
      gload_lds16(A + (size_t)(m0 + row) * 2048 + kk + cs * 8, As_ + ch * 8);
    }
#pragma unroll
    for (int j = 0; j < 2; j++) {
      int ch = j * 512 + tid, row = ch >> 3, c = ch & 7, cs = c ^ (row & 7);
      gload_lds16(B + (size_t)(n0 + row) * 2048 + kk + cs * 8, Bs_ + ch * 8);
    }
  };

  stage(0, 0);
  stage(1, 1);  // 12 loads/thread in flight

  for (int t = 0; t < 32; t++) {
    int cur = t & 1;
    bf16* As_ = S + cur * 16384;
    bf16* Bs_ = S + 32768 + cur * 8192;

    if (t < 31) { WAITVM(6); } else { WAITVM(0); }  // drain t, keep t+1 flying
    SBAR;
    bf16x8 aF[4][2], bF[4][2];
#pragma unroll
    for (int mi = 0; mi < 4; mi++)
#pragma unroll
      for (int kk = 0; kk < 2; kk++) {
        int row = wmi * 64 + mi * 16 + qr;
        aF[mi][kk] = *(bf16x8*)&As_[row * 64 + ((kk * 4 + quad) ^ (row & 7)) * 8];
      }
#pragma unroll
    for (int ni = 0; ni < 4; ni++)
#pragma unroll
      for (int kk = 0; kk < 2; kk++) {
        int row = wni * 64 + ni * 16 + qr;
        bF[ni][kk] = *(bf16x8*)&Bs_[row * 64 + ((kk * 4 + quad) ^ (row & 7)) * 8];
      }
    WAITLGKM0;
    SBAR;  // all waves done reading buf cur -> safe to overwrite
    if (t < 30) stage(t + 2, cur);
    SCHEDB;
    PRIO(1);
#pragma unroll
    for (int kk = 0; kk < 2; kk++)
#pragma unroll
      for (int mi = 0; mi < 4; mi++)
#pragma unroll
        for (int ni = 0; ni < 4; ni++)
          acc[mi][ni] = MFMA(aF[mi][kk], bF[ni][kk], acc[mi][ni]);
    PRIO(0);
  }

  // publish Linv via LDS reuse (all reads/stages retired past last barrier)
  WAITLGKM0;
  SBAR;
  float* Linv_s = (float*)S;
  if (tid < 256) Linv_s[tid] = linv_own;
  SBAR;

#pragma unroll
  for (int mi = 0; mi < 4; mi++) {
    int rowl = wmi * 64 + mi * 16 + quad * 4;  // local q row base (0..255)
    float linv[4];
    for (int r = 0; r < 4; r++) linv[r] = Linv_s[rowl + r];
#pragma unroll
    for (int ni = 0; ni < 4; ni++) {
      int col = n0 + wni * 64 + ni * 16 + qr;
      float* og = out + (size_t)(b * 2048 + m0 + rowl) * 512 + col;
      for (int r = 0; r < 4; r++) og[(size_t)r * 512] = acc[mi][ni][r] * linv[r];
    }
  }
}

// ---------------------------------------------------------------------------
extern "C" void kernel_launch(void* const* d_in, const int* in_sizes, int n_in,
                              void* d_out, int out_size, void* d_ws, size_t ws_size,
                              hipStream_t stream) {
  (void)in_sizes; (void)n_in; (void)out_size; (void)ws_size;
  const float* q  = (const float*)d_in[0];
  const float* k  = (const float*)d_in[1];
  const float* v  = (const float*)d_in[2];
  const float* Wq = (const float*)d_in[3];
  const float* bq = (const float*)d_in[4];
  const float* Wk = (const float*)d_in[5];
  const float* bk = (const float*)d_in[6];
  const float* Wv = (const float*)d_in[7];
  const float* bv = (const float*)d_in[8];
  float* out = (float*)d_out;

  char* ws = (char*)d_ws;
  bf16* Wt     = (bf16*)(ws);                 // 1,572,864 B
  bf16* Qp     = (bf16*)(ws + 1572864);       // 16 MiB
  bf16* Kp     = (bf16*)(ws + 18350080);      // 16 MiB
  bf16* Vtp    = (bf16*)(ws + 35127296);      // 16 MiB (written by k_proj z=2)
  bf16* P      = (bf16*)(ws + 51904512);      // 64 MiB
  float* Lpart = (float*)(ws + 119013376);    // 2 MiB  (total ~115.4 MiB)

  k_wtrans<<<dim3(16, 16, 3), dim3(32, 8, 1), 0, stream>>>(Wq, Wk, Wv, Wt);
  k_proj<<<dim3(128, 4, 3), 256, 0, stream>>>(q, k, v, Wt, bq, bk, bv, Qp, Kp, Vtp);
  k_qk<<<dim3(8, 8, 8), 512, 0, stream>>>(Qp, Kp, P, Lpart);
  k_pv<<<dim3(8, 4, 8), 512, 0, stream>>>(P, Vtp, Lpart, out);
}